// Round 18
// baseline (133.262 us; speedup 1.0000x reference)
//
#include <hip/hip_runtime.h>

#define N_NODES 50000
#define N_EDGES 800000
#define IN_CH 128
#define HID 64
#define OUT_CH 40
#define BSHIFT 7
#define BNODES 128    // nodes per bucket
#define NBUCKETS 391  // ceil(50000/128)
#define NBLK 256      // edge-pass blocks
#define EPB 3125      // edges per block (256*3125 = 800000 exactly)
#define NSEG (NBUCKETS * NBLK)  // 100096 (bucket-major: i = (b<<8)|blk)
#define SCHUNK 1024
#define NSCANA ((NSEG + SCHUNK - 1) / SCHUNK)  // 98
#define MAXB 4096     // placeC LDS slot capacity (expected 2048, +45 sigma)
#define NXBLK 782     // ceil(50000/64) xform1 blocks

// ---------------------------------------------------------------------------
// CSR gather, no fp atomics, transform-before-aggregate.
//   histX:  [blocks 0..255] per-block LDS bucket histogram  (overlapped with)
//           [blocks 256+ ]  MFMA xform1: xwl=bf16(x@W1l.T), xwr=x@W1r.T+b1
//   scanA/B: 2-level scan of blkcnt; consumers add asum[i>>10] themselves
//            (r17: scanC folded into placeB/placeC cursor init)
//   placeB: LDS cursors; packed (src<<7|dstlocal) pairs -> contiguous segments
//   placeC: per bucket: LDS degree count + scan -> cnt/off; LDS-place -> csr
//   agg1:   h1 = relu(gather_mean(xwl) + xwr)   [1 node/wave, paired-uint]
//   xform2: hw2 = bf16(h1@W2l.T), self2 = h1@W2r.T + b2
//   agg2:   out = log_softmax(gather_mean(hw2) + self2)
//           [3 edges/wave-slot: eslot=lane/20, cp=lane%20, uint loads]
// ---------------------------------------------------------------------------

typedef __attribute__((ext_vector_type(8))) short short8v;
typedef __attribute__((ext_vector_type(4))) float float4v;

__device__ __forceinline__ unsigned f2bf_u(float f) {
  unsigned u = __float_as_uint(f);
  return (u + 0x7FFF + ((u >> 16) & 1)) >> 16;  // RNE
}
__device__ __forceinline__ ushort f2bf(float f) { return (ushort)f2bf_u(f); }
__device__ __forceinline__ float bf2f(ushort u) {
  return __uint_as_float(((unsigned)u) << 16);
}
__device__ __forceinline__ float bflo(unsigned u) {
  return __uint_as_float(u << 16);
}
__device__ __forceinline__ float bfhi(unsigned u) {
  return __uint_as_float(u & 0xFFFF0000u);
}

// pack 8 consecutive floats -> 8 bf16 in a uint4
__device__ __forceinline__ uint4 pack8(const float* p) {
  float4 a = *reinterpret_cast<const float4*>(p);
  float4 b = *reinterpret_cast<const float4*>(p + 4);
  uint4 r;
  r.x = f2bf_u(a.x) | (f2bf_u(a.y) << 16);
  r.y = f2bf_u(a.z) | (f2bf_u(a.w) << 16);
  r.z = f2bf_u(b.x) | (f2bf_u(b.y) << 16);
  r.w = f2bf_u(b.z) | (f2bf_u(b.w) << 16);
  return r;
}

// merged: blocks [0,NBLK) histogram; blocks [NBLK, NBLK+NXBLK) MFMA xform1
__global__ __launch_bounds__(256) void histX_kernel(
    const int* __restrict__ dst, int* __restrict__ blkcnt,
    const float* __restrict__ x, const float* __restrict__ W1l,
    const float* __restrict__ W1r, const float* __restrict__ b1,
    ushort* __restrict__ xwl, float* __restrict__ xwr) {
  __shared__ int h[NBUCKETS];
  __shared__ ushort sWl[64 * 128];  // 16 KB, swizzle byte^=(row&15)<<4
  __shared__ ushort sWr[64 * 128];
  __shared__ ushort sx[64 * 128];
  __shared__ float sb[64];

  if (blockIdx.x < NBLK) {
    // ---- histogram path ----
    for (int i = threadIdx.x; i < NBUCKETS; i += 256) h[i] = 0;
    __syncthreads();
    int blk = blockIdx.x;
    int e0 = blk * EPB, e1 = min(e0 + EPB, N_EDGES);
    for (int e = e0 + threadIdx.x; e < e1; e += 256)
      atomicAdd(&h[dst[e] >> BSHIFT], 1);
    __syncthreads();
    for (int i = threadIdx.x; i < NBUCKETS; i += 256)
      blkcnt[(i << 8) | blk] = h[i];
    return;
  }

  // ---- MFMA xform1 path ----
  int nblk = (blockIdx.x - NBLK) * 64;
  for (int q = threadIdx.x; q < 1024; q += 256) {
    int row = q >> 4, c8 = (q & 15) << 3;
    int boff = row * 256 + (((c8 << 1)) ^ ((row & 15) << 4));
    int n = nblk + row;
    uint4 p = make_uint4(0, 0, 0, 0);
    if (n < N_NODES) p = pack8(x + (size_t)n * IN_CH + c8);
    *reinterpret_cast<uint4*>((char*)sx + boff) = p;
  }
  for (int q = threadIdx.x; q < 1024; q += 256) {
    int row = q >> 4, c8 = (q & 15) << 3;
    int boff = row * 256 + (((c8 << 1)) ^ ((row & 15) << 4));
    *reinterpret_cast<uint4*>((char*)sWl + boff) =
        pack8(W1l + row * IN_CH + c8);
    *reinterpret_cast<uint4*>((char*)sWr + boff) =
        pack8(W1r + row * IN_CH + c8);
  }
  if (threadIdx.x < 64) sb[threadIdx.x] = b1[threadIdx.x];
  __syncthreads();

  int wave = threadIdx.x >> 6, lane = threadIdx.x & 63;
  int nloc = lane & 15, g = lane >> 4;

  float4v accl[4], accr[4];
#pragma unroll
  for (int m = 0; m < 4; ++m) {
    accl[m] = (float4v){0.f, 0.f, 0.f, 0.f};
    accr[m] = (float4v){0.f, 0.f, 0.f, 0.f};
  }

  int xrow = wave * 16 + nloc;
#pragma unroll
  for (int kt = 0; kt < 4; ++kt) {
    int cb = kt * 64 + g * 16;
    short8v bx = *reinterpret_cast<const short8v*>(
        (char*)sx + xrow * 256 + (cb ^ ((xrow & 15) << 4)));
#pragma unroll
    for (int m = 0; m < 4; ++m) {
      int wrow = m * 16 + nloc;
      int so = wrow * 256 + (cb ^ ((wrow & 15) << 4));
      short8v al = *reinterpret_cast<const short8v*>((char*)sWl + so);
      short8v ar = *reinterpret_cast<const short8v*>((char*)sWr + so);
      accl[m] = __builtin_amdgcn_mfma_f32_16x16x32_bf16(al, bx, accl[m], 0, 0, 0);
      accr[m] = __builtin_amdgcn_mfma_f32_16x16x32_bf16(ar, bx, accr[m], 0, 0, 0);
    }
  }

  int n = nblk + wave * 16 + nloc;
  if (n < N_NODES) {
#pragma unroll
    for (int m = 0; m < 4; ++m) {
      int h0 = m * 16 + g * 4;
      uint2 pl;
      pl.x = f2bf_u(accl[m][0]) | (f2bf_u(accl[m][1]) << 16);
      pl.y = f2bf_u(accl[m][2]) | (f2bf_u(accl[m][3]) << 16);
      *reinterpret_cast<uint2*>(xwl + (size_t)n * HID + h0) = pl;
      float4 vr;
      vr.x = accr[m][0] + sb[h0 + 0];
      vr.y = accr[m][1] + sb[h0 + 1];
      vr.z = accr[m][2] + sb[h0 + 2];
      vr.w = accr[m][3] + sb[h0 + 3];
      *reinterpret_cast<float4*>(xwr + (size_t)n * HID + h0) = vr;
    }
  }
}

// level-1 scan: 1024 elems/block (4/thread, coalesced)
__global__ __launch_bounds__(256) void scanA_kernel(
    const int* __restrict__ blkcnt, int* __restrict__ segoff,
    int* __restrict__ asum) {
  __shared__ int s[256];
  int t = threadIdx.x;
  int idx0 = blockIdx.x * SCHUNK + t * 4;
  int v[4], tot = 0;
#pragma unroll
  for (int j = 0; j < 4; ++j) {
    int i = idx0 + j;
    v[j] = (i < NSEG) ? blkcnt[i] : 0;
    tot += v[j];
  }
  s[t] = tot;
  __syncthreads();
  for (int o = 1; o < 256; o <<= 1) {
    int u = (t >= o) ? s[t - o] : 0;
    __syncthreads();
    s[t] += u;
    __syncthreads();
  }
  int pre = s[t] - tot;
#pragma unroll
  for (int j = 0; j < 4; ++j) {
    int i = idx0 + j;
    if (i < NSEG) segoff[i] = pre;
    pre += v[j];
  }
  if (t == 255) asum[blockIdx.x] = s[255];
}

// level-2: scan the 98 block sums (tiny)
__global__ __launch_bounds__(256) void scanB_kernel(int* __restrict__ asum) {
  __shared__ int s[256];
  int t = threadIdx.x;
  int v = (t < NSCANA) ? asum[t] : 0;
  s[t] = v;
  __syncthreads();
  for (int o = 1; o < 256; o <<= 1) {
    int u = (t >= o) ? s[t - o] : 0;
    __syncthreads();
    s[t] += u;
    __syncthreads();
  }
  if (t < NSCANA) asum[t] = s[t] - v;
}

// bin packed pairs into per-(block,bucket) contiguous segments (LDS cursors);
// global segment offset = segoff[i] + asum[i>>10]  (scanC folded in here)
__global__ __launch_bounds__(256) void placeB_kernel(
    const int* __restrict__ src, const int* __restrict__ dst,
    const int* __restrict__ segoff, const int* __restrict__ asum,
    unsigned* __restrict__ pairbuf) {
  __shared__ int cur[NBUCKETS];
  int blk = blockIdx.x;
  for (int b = threadIdx.x; b < NBUCKETS; b += 256) {
    int i = (b << 8) | blk;
    cur[b] = segoff[i] + asum[i >> 10];
  }
  __syncthreads();
  int e0 = blk * EPB, e1 = min(e0 + EPB, N_EDGES);
  for (int e = e0 + threadIdx.x; e < e1; e += 256) {
    int d = dst[e];
    int pos = atomicAdd(&cur[d >> BSHIFT], 1);  // LDS atomic
    pairbuf[pos] = ((unsigned)src[e] << BSHIFT) | (unsigned)(d & (BNODES - 1));
  }
}

// per bucket: degree-count + LDS scan -> cnt/off (coalesced); place -> csr
__global__ __launch_bounds__(256) void placeC_kernel(
    const unsigned* __restrict__ pairbuf, const int* __restrict__ segoff,
    const int* __restrict__ asum, int* __restrict__ cnt,
    int* __restrict__ off, int* __restrict__ csr) {
  __shared__ int lcnt[BNODES];
  __shared__ int woff[BNODES];
  __shared__ int lcur[BNODES];
  __shared__ int sscan[256];
  __shared__ int slot[MAXB];
  int b = blockIdx.x;
  int i0 = b << 8;
  int start = segoff[i0] + asum[i0 >> 10];
  int end = N_EDGES;
  if (b != NBUCKETS - 1) {
    int i1 = (b + 1) << 8;
    end = segoff[i1] + asum[i1 >> 10];
  }
  int n0 = b << BSHIFT;
  int nn = min(BNODES, N_NODES - n0);
  int len = end - start;
  for (int i = threadIdx.x; i < nn; i += 256) {
    lcnt[i] = 0;
    lcur[i] = 0;
  }
  __syncthreads();
  for (int p = start + threadIdx.x; p < end; p += 256)
    atomicAdd(&lcnt[pairbuf[p] & (BNODES - 1)], 1);
  __syncthreads();
  int v = (threadIdx.x < nn) ? lcnt[threadIdx.x] : 0;
  sscan[threadIdx.x] = v;
  __syncthreads();
  for (int o = 1; o < 256; o <<= 1) {
    int t2 = (threadIdx.x >= o) ? sscan[threadIdx.x - o] : 0;
    __syncthreads();
    sscan[threadIdx.x] += t2;
    __syncthreads();
  }
  if (threadIdx.x < nn) {
    woff[threadIdx.x] = sscan[threadIdx.x] - v;
    cnt[n0 + threadIdx.x] = v;
    off[n0 + threadIdx.x] = start + sscan[threadIdx.x] - v;
  }
  __syncthreads();
  if (len <= MAXB) {
    for (int p = start + threadIdx.x; p < end; p += 256) {
      unsigned e = pairbuf[p];
      int local = (int)(e & (BNODES - 1));
      int pos = woff[local] + atomicAdd(&lcur[local], 1);
      slot[pos] = (int)(e >> BSHIFT);
    }
    __syncthreads();
    for (int p = threadIdx.x; p < len; p += 256) csr[start + p] = slot[p];
  } else {  // statistical-overflow fallback
    for (int p = start + threadIdx.x; p < end; p += 256) {
      unsigned e = pairbuf[p];
      int local = (int)(e & (BNODES - 1));
      int pos = woff[local] + atomicAdd(&lcur[local], 1);
      csr[start + pos] = (int)(e >> BSHIFT);
    }
  }
}

// h1 = relu(gather_mean(xwl) + xwr) — lean gather, 1 node/wave, 16-wide MLP
__global__ __launch_bounds__(256) void agg1_kernel(
    const ushort* __restrict__ xwl, const float* __restrict__ xwr,
    const int* __restrict__ cnt, const int* __restrict__ off,
    const int* __restrict__ csr, float* __restrict__ h1) {
  int wave = threadIdx.x >> 6, lane = threadIdx.x & 63;
  int n = blockIdx.x * 4 + wave;
  if (n >= N_NODES) return;

  int deg = cnt[n], base = off[n];
  int half = lane >> 5;
  int cp = lane & 31;
  float ax = 0.f, ay = 0.f;

  if (deg > 0) {
    int k = 0;
    for (; k + 16 <= deg; k += 16) {  // 8 edge-pairs in flight
      int e[8];
#pragma unroll
      for (int j = 0; j < 8; ++j) e[j] = csr[base + k + 2 * j + half];
      unsigned u[8];
#pragma unroll
      for (int j = 0; j < 8; ++j)
        u[j] = *reinterpret_cast<const unsigned*>(xwl + (size_t)e[j] * HID +
                                                  2 * cp);
#pragma unroll
      for (int j = 0; j < 8; ++j) {
        ax += bflo(u[j]);
        ay += bfhi(u[j]);
      }
    }
    if (k + 8 <= deg) {
      int e[4];
#pragma unroll
      for (int j = 0; j < 4; ++j) e[j] = csr[base + k + 2 * j + half];
      unsigned u[4];
#pragma unroll
      for (int j = 0; j < 4; ++j)
        u[j] = *reinterpret_cast<const unsigned*>(xwl + (size_t)e[j] * HID +
                                                  2 * cp);
#pragma unroll
      for (int j = 0; j < 4; ++j) {
        ax += bflo(u[j]);
        ay += bfhi(u[j]);
      }
      k += 8;
    }
    if (k < deg) {  // masked remainder (<8 edges)
#pragma unroll
      for (int j = 0; j < 4; ++j) {
        int idx = k + 2 * j + half;
        bool valid = idx < deg;
        int e = csr[base + (valid ? idx : 0)];
        unsigned u =
            *reinterpret_cast<const unsigned*>(xwl + (size_t)e * HID + 2 * cp);
        if (valid) {
          ax += bflo(u);
          ay += bfhi(u);
        }
      }
    }
    ax += __shfl_xor(ax, 32);
    ay += __shfl_xor(ay, 32);
  }

  float inv = 1.0f / fmaxf((float)deg, 1.0f);
  const float2 s =
      *reinterpret_cast<const float2*>(xwr + (size_t)n * HID + 2 * cp);
  float2 h;
  h.x = fmaxf(ax * inv + s.x, 0.f);
  h.y = fmaxf(ay * inv + s.y, 0.f);
  if (half == 0)
    *reinterpret_cast<float2*>(h1 + (size_t)n * HID + 2 * cp) = h;
}

// hw2[n,o] = bf16(h1[n,:].W2l[o,:]);  self2[n,o] = h1[n,:].W2r[o,:] + b2[o]
__global__ __launch_bounds__(256) void xform2_kernel(
    const float* __restrict__ h1, const float* __restrict__ W2l,
    const float* __restrict__ W2r, const float* __restrict__ b2,
    ushort* __restrict__ hw2, float* __restrict__ self2) {
  __shared__ unsigned sWl[HID / 2][OUT_CH + 1];
  __shared__ unsigned sWr[HID / 2][OUT_CH + 1];
  __shared__ float sh[32][HID];
  for (int i = threadIdx.x; i < OUT_CH * (HID / 2); i += 256) {
    int o = i >> 5, c2 = i & 31;
    float a = W2l[o * HID + 2 * c2], b = W2l[o * HID + 2 * c2 + 1];
    sWl[c2][o] = (unsigned)f2bf(a) | ((unsigned)f2bf(b) << 16);
    float c = W2r[o * HID + 2 * c2], d = W2r[o * HID + 2 * c2 + 1];
    sWr[c2][o] = (unsigned)f2bf(c) | ((unsigned)f2bf(d) << 16);
  }
  int nblk = blockIdx.x * 32;
  for (int s = threadIdx.x; s < 32 * (HID / 4); s += 256) {
    int node = s >> 4, c4 = s & 15;
    int n = nblk + node;
    float4 v = make_float4(0.f, 0.f, 0.f, 0.f);
    if (n < N_NODES)
      v = *reinterpret_cast<const float4*>(h1 + (size_t)n * HID + c4 * 4);
    *reinterpret_cast<float4*>(&sh[node][c4 * 4]) = v;
  }
  __syncthreads();

  int wave = threadIdx.x >> 6, lane = threadIdx.x & 63;
  int n0 = nblk + wave * 8;
  if (n0 >= N_NODES || lane >= OUT_CH) return;
  float bias = b2[lane];

  float accl[8], accr[8];
#pragma unroll
  for (int i = 0; i < 8; ++i) {
    accl[i] = 0.f;
    accr[i] = bias;
  }
  const int nb = wave * 8;
  int nvalid = min(8, N_NODES - n0);
  for (int c = 0; c < HID; c += 4) {
    unsigned ul0 = sWl[(c >> 1) + 0][lane], ul1 = sWl[(c >> 1) + 1][lane];
    unsigned ur0 = sWr[(c >> 1) + 0][lane], ur1 = sWr[(c >> 1) + 1][lane];
    float wl0 = bflo(ul0), wl1 = bfhi(ul0), wl2 = bflo(ul1), wl3 = bfhi(ul1);
    float wr0 = bflo(ur0), wr1 = bfhi(ur0), wr2 = bflo(ur1), wr3 = bfhi(ur1);
#pragma unroll
    for (int i = 0; i < 8; ++i) {
      const float4 hv = *reinterpret_cast<const float4*>(&sh[nb + i][c]);
      accl[i] = fmaf(hv.x, wl0, accl[i]);
      accr[i] = fmaf(hv.x, wr0, accr[i]);
      accl[i] = fmaf(hv.y, wl1, accl[i]);
      accr[i] = fmaf(hv.y, wr1, accr[i]);
      accl[i] = fmaf(hv.z, wl2, accl[i]);
      accr[i] = fmaf(hv.z, wr2, accr[i]);
      accl[i] = fmaf(hv.w, wl3, accl[i]);
      accr[i] = fmaf(hv.w, wr3, accr[i]);
    }
  }
  for (int i = 0; i < nvalid; ++i) {
    hw2[(size_t)(n0 + i) * OUT_CH + lane] = f2bf(accl[i]);
    self2[(size_t)(n0 + i) * OUT_CH + lane] = accr[i];
  }
}

// out = log_softmax(gather_mean(hw2) + self2)
// 3 edges per issue slot: eslot = lane/20 (0..2), cp = lane%20 (channel pair).
// uint loads (2 ch); shfl-fold eslots; 20-lane paired log-softmax.
__global__ __launch_bounds__(256) void agg2_kernel(
    const ushort* __restrict__ hw2, const float* __restrict__ self2,
    const int* __restrict__ cnt, const int* __restrict__ off,
    const int* __restrict__ csr, float* __restrict__ out) {
  int wave = threadIdx.x >> 6, lane = threadIdx.x & 63;
  int n = blockIdx.x * 4 + wave;
  if (n >= N_NODES) return;

  int deg = cnt[n], base = off[n];
  int eslot = lane / 20;        // 0..3 (eslot 3 = lanes 60..63, idle)
  int cp = lane - eslot * 20;   // 0..19
  bool act = eslot < 3;
  float ax = 0.f, ay = 0.f;

  for (int k = 0; k < deg; k += 12) {  // 12 edges in flight (4 iters x 3)
#pragma unroll
    for (int j = 0; j < 4; ++j) {
      int idx = k + 3 * j + eslot;
      bool valid = act && idx < deg;
      int e = csr[base + (valid ? idx : 0)];
      unsigned u = *reinterpret_cast<const unsigned*>(
          hw2 + (size_t)e * OUT_CH + 2 * cp);
      if (valid) {
        ax += bflo(u);
        ay += bfhi(u);
      }
    }
  }
  // fold eslot 1,2 into eslot 0 (lanes < 20)
  float t1 = __shfl(ax, cp + 20), t2 = __shfl(ax, cp + 40);
  float t3 = __shfl(ay, cp + 20), t4 = __shfl(ay, cp + 40);
  ax += t1 + t2;
  ay += t3 + t4;

  float lx = -1e30f, ly = -1e30f;
  if (lane < 20) {
    float inv = 1.0f / fmaxf((float)deg, 1.0f);
    const float2 s =
        *reinterpret_cast<const float2*>(self2 + (size_t)n * OUT_CH + 2 * cp);
    lx = ax * inv + s.x;
    ly = ay * inv + s.y;
  }
  // log_softmax over 40 channels held as 20 lanes x 2
  float m = fmaxf(lx, ly);
  for (int o = 32; o; o >>= 1) m = fmaxf(m, __shfl_xor(m, o));
  float ssum = (lane < 20) ? (expf(lx - m) + expf(ly - m)) : 0.f;
  for (int o = 32; o; o >>= 1) ssum += __shfl_xor(ssum, o);
  float lse = logf(ssum);
  if (lane < 20) {
    float2 r;
    r.x = lx - m - lse;
    r.y = ly - m - lse;
    *reinterpret_cast<float2*>(out + (size_t)n * OUT_CH + 2 * cp) = r;
  }
}

extern "C" void kernel_launch(void* const* d_in, const int* in_sizes, int n_in,
                              void* d_out, int out_size, void* d_ws, size_t ws_size,
                              hipStream_t stream) {
  const float* x   = (const float*)d_in[0];
  const int*   ei  = (const int*)d_in[1];
  const float* W1l = (const float*)d_in[2];
  const float* b1  = (const float*)d_in[3];
  const float* W1r = (const float*)d_in[4];
  const float* W2l = (const float*)d_in[5];
  const float* b2  = (const float*)d_in[6];
  const float* W2r = (const float*)d_in[7];
  float* out = (float*)d_out;

  const int* src = ei;            // edge_index[0]
  const int* dst = ei + N_EDGES;  // edge_index[1]

  // ws layout — pairbuf does not alias xwr (xform1 runs inside histX)
  float* xwr   = (float*)d_ws;                             // [N*HID] f32
  float* self2 = xwr + (size_t)N_NODES * HID;              // [N*OUT_CH] f32
  float* h1    = self2 + (size_t)N_NODES * OUT_CH;         // [N*HID] f32
  ushort* xwl  = (ushort*)(h1 + (size_t)N_NODES * HID);    // [N*HID] bf16
  ushort* hw2  = xwl + (size_t)N_NODES * HID;              // [N*OUT_CH] bf16
  unsigned* pairbuf = (unsigned*)(hw2 + (size_t)N_NODES * OUT_CH);  // [E]
  int* blkcnt = (int*)(pairbuf + N_EDGES);                 // [NSEG]
  int* segoff = blkcnt + NSEG;                             // [NSEG]
  int* asum   = segoff + NSEG;                             // [256]
  int* cnt    = asum + 256;                                // [N]
  int* off    = cnt + N_NODES;                             // [N]
  int* csr    = off + N_NODES;                             // [E]

  // merged histogram + xform1 (independent work, overlapped)
  histX_kernel<<<NBLK + NXBLK, 256, 0, stream>>>(dst, blkcnt, x, W1l, W1r, b1,
                                                 xwl, xwr);
  scanA_kernel<<<NSCANA, 256, 0, stream>>>(blkcnt, segoff, asum);
  scanB_kernel<<<1, 256, 0, stream>>>(asum);
  placeB_kernel<<<NBLK, 256, 0, stream>>>(src, dst, segoff, asum, pairbuf);
  placeC_kernel<<<NBUCKETS, 256, 0, stream>>>(pairbuf, segoff, asum, cnt, off,
                                              csr);

  agg1_kernel<<<(N_NODES + 3) / 4, 256, 0, stream>>>(xwl, xwr, cnt, off, csr,
                                                     h1);
  xform2_kernel<<<(N_NODES + 31) / 32, 256, 0, stream>>>(h1, W2l, W2r, b2, hw2,
                                                         self2);
  agg2_kernel<<<(N_NODES + 3) / 4, 256, 0, stream>>>(hw2, self2, cnt, off, csr,
                                                     out);
}

// Round 19
// 119.283 us; speedup vs baseline: 1.1172x; 1.1172x over previous
//
#include <hip/hip_runtime.h>

#define N_NODES 50000
#define N_EDGES 800000
#define IN_CH 128
#define HID 64
#define OUT_CH 40
#define BSHIFT 7
#define BNODES 128    // nodes per bucket
#define NBUCKETS 391  // ceil(50000/128)
#define NBLK 256      // edge-pass blocks
#define EPB 3125      // edges per block (256*3125 = 800000 exactly)
#define NSEG (NBUCKETS * NBLK)  // 100096 (bucket-major: i = (b<<8)|blk)
#define SCHUNK 1024
#define NSCANA ((NSEG + SCHUNK - 1) / SCHUNK)  // 98
#define MAXB 4096     // placeC LDS slot capacity (expected 2048, +45 sigma)
#define NXBLK 782     // ceil(50000/64) xform1 blocks

// ---------------------------------------------------------------------------
// CSR gather, no fp atomics, transform-before-aggregate.
//   histX:  [blocks 0..255] per-block LDS bucket histogram  (overlapped with)
//           [blocks 256+ ]  MFMA xform1: xwl=bf16(x@W1l.T), xwr=x@W1r.T+b1
//   scanA/B: 2-level scan of blkcnt; consumers add asum[i>>10] themselves
//   placeB: LDS cursors; packed (src<<7|dstlocal) pairs -> contiguous segments
//   placeC: per bucket: LDS degree count + scan -> cnt/off; LDS-place -> csr
//   agg1:   h1 = relu(gather_mean(xwl) + xwr)   [1 node/wave, paired-uint]
//   xform2: hw2 = bf16(h1@W2l.T), self2 = h1@W2r.T + b2
//   agg2:   out = log_softmax(gather_mean(hw2) + self2)  [16-wide exact-deg;
//           r18 lesson: masked always-issue 12-strides waste 50% at deg~16]
// ---------------------------------------------------------------------------

typedef __attribute__((ext_vector_type(8))) short short8v;
typedef __attribute__((ext_vector_type(4))) float float4v;

__device__ __forceinline__ unsigned f2bf_u(float f) {
  unsigned u = __float_as_uint(f);
  return (u + 0x7FFF + ((u >> 16) & 1)) >> 16;  // RNE
}
__device__ __forceinline__ ushort f2bf(float f) { return (ushort)f2bf_u(f); }
__device__ __forceinline__ float bf2f(ushort u) {
  return __uint_as_float(((unsigned)u) << 16);
}
__device__ __forceinline__ float bflo(unsigned u) {
  return __uint_as_float(u << 16);
}
__device__ __forceinline__ float bfhi(unsigned u) {
  return __uint_as_float(u & 0xFFFF0000u);
}

// pack 8 consecutive floats -> 8 bf16 in a uint4
__device__ __forceinline__ uint4 pack8(const float* p) {
  float4 a = *reinterpret_cast<const float4*>(p);
  float4 b = *reinterpret_cast<const float4*>(p + 4);
  uint4 r;
  r.x = f2bf_u(a.x) | (f2bf_u(a.y) << 16);
  r.y = f2bf_u(a.z) | (f2bf_u(a.w) << 16);
  r.z = f2bf_u(b.x) | (f2bf_u(b.y) << 16);
  r.w = f2bf_u(b.z) | (f2bf_u(b.w) << 16);
  return r;
}

// merged: blocks [0,NBLK) histogram; blocks [NBLK, NBLK+NXBLK) MFMA xform1
__global__ __launch_bounds__(256) void histX_kernel(
    const int* __restrict__ dst, int* __restrict__ blkcnt,
    const float* __restrict__ x, const float* __restrict__ W1l,
    const float* __restrict__ W1r, const float* __restrict__ b1,
    ushort* __restrict__ xwl, float* __restrict__ xwr) {
  __shared__ int h[NBUCKETS];
  __shared__ ushort sWl[64 * 128];  // 16 KB, swizzle byte^=(row&15)<<4
  __shared__ ushort sWr[64 * 128];
  __shared__ ushort sx[64 * 128];
  __shared__ float sb[64];

  if (blockIdx.x < NBLK) {
    // ---- histogram path ----
    for (int i = threadIdx.x; i < NBUCKETS; i += 256) h[i] = 0;
    __syncthreads();
    int blk = blockIdx.x;
    int e0 = blk * EPB, e1 = min(e0 + EPB, N_EDGES);
    for (int e = e0 + threadIdx.x; e < e1; e += 256)
      atomicAdd(&h[dst[e] >> BSHIFT], 1);
    __syncthreads();
    for (int i = threadIdx.x; i < NBUCKETS; i += 256)
      blkcnt[(i << 8) | blk] = h[i];
    return;
  }

  // ---- MFMA xform1 path ----
  int nblk = (blockIdx.x - NBLK) * 64;
  for (int q = threadIdx.x; q < 1024; q += 256) {
    int row = q >> 4, c8 = (q & 15) << 3;
    int boff = row * 256 + (((c8 << 1)) ^ ((row & 15) << 4));
    int n = nblk + row;
    uint4 p = make_uint4(0, 0, 0, 0);
    if (n < N_NODES) p = pack8(x + (size_t)n * IN_CH + c8);
    *reinterpret_cast<uint4*>((char*)sx + boff) = p;
  }
  for (int q = threadIdx.x; q < 1024; q += 256) {
    int row = q >> 4, c8 = (q & 15) << 3;
    int boff = row * 256 + (((c8 << 1)) ^ ((row & 15) << 4));
    *reinterpret_cast<uint4*>((char*)sWl + boff) =
        pack8(W1l + row * IN_CH + c8);
    *reinterpret_cast<uint4*>((char*)sWr + boff) =
        pack8(W1r + row * IN_CH + c8);
  }
  if (threadIdx.x < 64) sb[threadIdx.x] = b1[threadIdx.x];
  __syncthreads();

  int wave = threadIdx.x >> 6, lane = threadIdx.x & 63;
  int nloc = lane & 15, g = lane >> 4;

  float4v accl[4], accr[4];
#pragma unroll
  for (int m = 0; m < 4; ++m) {
    accl[m] = (float4v){0.f, 0.f, 0.f, 0.f};
    accr[m] = (float4v){0.f, 0.f, 0.f, 0.f};
  }

  int xrow = wave * 16 + nloc;
#pragma unroll
  for (int kt = 0; kt < 4; ++kt) {
    int cb = kt * 64 + g * 16;
    short8v bx = *reinterpret_cast<const short8v*>(
        (char*)sx + xrow * 256 + (cb ^ ((xrow & 15) << 4)));
#pragma unroll
    for (int m = 0; m < 4; ++m) {
      int wrow = m * 16 + nloc;
      int so = wrow * 256 + (cb ^ ((wrow & 15) << 4));
      short8v al = *reinterpret_cast<const short8v*>((char*)sWl + so);
      short8v ar = *reinterpret_cast<const short8v*>((char*)sWr + so);
      accl[m] = __builtin_amdgcn_mfma_f32_16x16x32_bf16(al, bx, accl[m], 0, 0, 0);
      accr[m] = __builtin_amdgcn_mfma_f32_16x16x32_bf16(ar, bx, accr[m], 0, 0, 0);
    }
  }

  int n = nblk + wave * 16 + nloc;
  if (n < N_NODES) {
#pragma unroll
    for (int m = 0; m < 4; ++m) {
      int h0 = m * 16 + g * 4;
      uint2 pl;
      pl.x = f2bf_u(accl[m][0]) | (f2bf_u(accl[m][1]) << 16);
      pl.y = f2bf_u(accl[m][2]) | (f2bf_u(accl[m][3]) << 16);
      *reinterpret_cast<uint2*>(xwl + (size_t)n * HID + h0) = pl;
      float4 vr;
      vr.x = accr[m][0] + sb[h0 + 0];
      vr.y = accr[m][1] + sb[h0 + 1];
      vr.z = accr[m][2] + sb[h0 + 2];
      vr.w = accr[m][3] + sb[h0 + 3];
      *reinterpret_cast<float4*>(xwr + (size_t)n * HID + h0) = vr;
    }
  }
}

// level-1 scan: 1024 elems/block (4/thread, coalesced)
__global__ __launch_bounds__(256) void scanA_kernel(
    const int* __restrict__ blkcnt, int* __restrict__ segoff,
    int* __restrict__ asum) {
  __shared__ int s[256];
  int t = threadIdx.x;
  int idx0 = blockIdx.x * SCHUNK + t * 4;
  int v[4], tot = 0;
#pragma unroll
  for (int j = 0; j < 4; ++j) {
    int i = idx0 + j;
    v[j] = (i < NSEG) ? blkcnt[i] : 0;
    tot += v[j];
  }
  s[t] = tot;
  __syncthreads();
  for (int o = 1; o < 256; o <<= 1) {
    int u = (t >= o) ? s[t - o] : 0;
    __syncthreads();
    s[t] += u;
    __syncthreads();
  }
  int pre = s[t] - tot;
#pragma unroll
  for (int j = 0; j < 4; ++j) {
    int i = idx0 + j;
    if (i < NSEG) segoff[i] = pre;
    pre += v[j];
  }
  if (t == 255) asum[blockIdx.x] = s[255];
}

// level-2: scan the 98 block sums (tiny)
__global__ __launch_bounds__(256) void scanB_kernel(int* __restrict__ asum) {
  __shared__ int s[256];
  int t = threadIdx.x;
  int v = (t < NSCANA) ? asum[t] : 0;
  s[t] = v;
  __syncthreads();
  for (int o = 1; o < 256; o <<= 1) {
    int u = (t >= o) ? s[t - o] : 0;
    __syncthreads();
    s[t] += u;
    __syncthreads();
  }
  if (t < NSCANA) asum[t] = s[t] - v;
}

// bin packed pairs into per-(block,bucket) contiguous segments (LDS cursors);
// global segment offset = segoff[i] + asum[i>>10]  (scanC folded in here)
__global__ __launch_bounds__(256) void placeB_kernel(
    const int* __restrict__ src, const int* __restrict__ dst,
    const int* __restrict__ segoff, const int* __restrict__ asum,
    unsigned* __restrict__ pairbuf) {
  __shared__ int cur[NBUCKETS];
  int blk = blockIdx.x;
  for (int b = threadIdx.x; b < NBUCKETS; b += 256) {
    int i = (b << 8) | blk;
    cur[b] = segoff[i] + asum[i >> 10];
  }
  __syncthreads();
  int e0 = blk * EPB, e1 = min(e0 + EPB, N_EDGES);
  for (int e = e0 + threadIdx.x; e < e1; e += 256) {
    int d = dst[e];
    int pos = atomicAdd(&cur[d >> BSHIFT], 1);  // LDS atomic
    pairbuf[pos] = ((unsigned)src[e] << BSHIFT) | (unsigned)(d & (BNODES - 1));
  }
}

// per bucket: degree-count + LDS scan -> cnt/off (coalesced); place -> csr
__global__ __launch_bounds__(256) void placeC_kernel(
    const unsigned* __restrict__ pairbuf, const int* __restrict__ segoff,
    const int* __restrict__ asum, int* __restrict__ cnt,
    int* __restrict__ off, int* __restrict__ csr) {
  __shared__ int lcnt[BNODES];
  __shared__ int woff[BNODES];
  __shared__ int lcur[BNODES];
  __shared__ int sscan[256];
  __shared__ int slot[MAXB];
  int b = blockIdx.x;
  int i0 = b << 8;
  int start = segoff[i0] + asum[i0 >> 10];
  int end = N_EDGES;
  if (b != NBUCKETS - 1) {
    int i1 = (b + 1) << 8;
    end = segoff[i1] + asum[i1 >> 10];
  }
  int n0 = b << BSHIFT;
  int nn = min(BNODES, N_NODES - n0);
  int len = end - start;
  for (int i = threadIdx.x; i < nn; i += 256) {
    lcnt[i] = 0;
    lcur[i] = 0;
  }
  __syncthreads();
  for (int p = start + threadIdx.x; p < end; p += 256)
    atomicAdd(&lcnt[pairbuf[p] & (BNODES - 1)], 1);
  __syncthreads();
  int v = (threadIdx.x < nn) ? lcnt[threadIdx.x] : 0;
  sscan[threadIdx.x] = v;
  __syncthreads();
  for (int o = 1; o < 256; o <<= 1) {
    int t2 = (threadIdx.x >= o) ? sscan[threadIdx.x - o] : 0;
    __syncthreads();
    sscan[threadIdx.x] += t2;
    __syncthreads();
  }
  if (threadIdx.x < nn) {
    woff[threadIdx.x] = sscan[threadIdx.x] - v;
    cnt[n0 + threadIdx.x] = v;
    off[n0 + threadIdx.x] = start + sscan[threadIdx.x] - v;
  }
  __syncthreads();
  if (len <= MAXB) {
    for (int p = start + threadIdx.x; p < end; p += 256) {
      unsigned e = pairbuf[p];
      int local = (int)(e & (BNODES - 1));
      int pos = woff[local] + atomicAdd(&lcur[local], 1);
      slot[pos] = (int)(e >> BSHIFT);
    }
    __syncthreads();
    for (int p = threadIdx.x; p < len; p += 256) csr[start + p] = slot[p];
  } else {  // statistical-overflow fallback
    for (int p = start + threadIdx.x; p < end; p += 256) {
      unsigned e = pairbuf[p];
      int local = (int)(e & (BNODES - 1));
      int pos = woff[local] + atomicAdd(&lcur[local], 1);
      csr[start + pos] = (int)(e >> BSHIFT);
    }
  }
}

// h1 = relu(gather_mean(xwl) + xwr) — lean gather, 1 node/wave, 16-wide MLP
__global__ __launch_bounds__(256) void agg1_kernel(
    const ushort* __restrict__ xwl, const float* __restrict__ xwr,
    const int* __restrict__ cnt, const int* __restrict__ off,
    const int* __restrict__ csr, float* __restrict__ h1) {
  int wave = threadIdx.x >> 6, lane = threadIdx.x & 63;
  int n = blockIdx.x * 4 + wave;
  if (n >= N_NODES) return;

  int deg = cnt[n], base = off[n];
  int half = lane >> 5;
  int cp = lane & 31;
  float ax = 0.f, ay = 0.f;

  if (deg > 0) {
    int k = 0;
    for (; k + 16 <= deg; k += 16) {  // 8 edge-pairs in flight
      int e[8];
#pragma unroll
      for (int j = 0; j < 8; ++j) e[j] = csr[base + k + 2 * j + half];
      unsigned u[8];
#pragma unroll
      for (int j = 0; j < 8; ++j)
        u[j] = *reinterpret_cast<const unsigned*>(xwl + (size_t)e[j] * HID +
                                                  2 * cp);
#pragma unroll
      for (int j = 0; j < 8; ++j) {
        ax += bflo(u[j]);
        ay += bfhi(u[j]);
      }
    }
    if (k + 8 <= deg) {
      int e[4];
#pragma unroll
      for (int j = 0; j < 4; ++j) e[j] = csr[base + k + 2 * j + half];
      unsigned u[4];
#pragma unroll
      for (int j = 0; j < 4; ++j)
        u[j] = *reinterpret_cast<const unsigned*>(xwl + (size_t)e[j] * HID +
                                                  2 * cp);
#pragma unroll
      for (int j = 0; j < 4; ++j) {
        ax += bflo(u[j]);
        ay += bfhi(u[j]);
      }
      k += 8;
    }
    if (k < deg) {  // masked remainder (<8 edges)
#pragma unroll
      for (int j = 0; j < 4; ++j) {
        int idx = k + 2 * j + half;
        bool valid = idx < deg;
        int e = csr[base + (valid ? idx : 0)];
        unsigned u =
            *reinterpret_cast<const unsigned*>(xwl + (size_t)e * HID + 2 * cp);
        if (valid) {
          ax += bflo(u);
          ay += bfhi(u);
        }
      }
    }
    ax += __shfl_xor(ax, 32);
    ay += __shfl_xor(ay, 32);
  }

  float inv = 1.0f / fmaxf((float)deg, 1.0f);
  const float2 s =
      *reinterpret_cast<const float2*>(xwr + (size_t)n * HID + 2 * cp);
  float2 h;
  h.x = fmaxf(ax * inv + s.x, 0.f);
  h.y = fmaxf(ay * inv + s.y, 0.f);
  if (half == 0)
    *reinterpret_cast<float2*>(h1 + (size_t)n * HID + 2 * cp) = h;
}

// hw2[n,o] = bf16(h1[n,:].W2l[o,:]);  self2[n,o] = h1[n,:].W2r[o,:] + b2[o]
__global__ __launch_bounds__(256) void xform2_kernel(
    const float* __restrict__ h1, const float* __restrict__ W2l,
    const float* __restrict__ W2r, const float* __restrict__ b2,
    ushort* __restrict__ hw2, float* __restrict__ self2) {
  __shared__ unsigned sWl[HID / 2][OUT_CH + 1];
  __shared__ unsigned sWr[HID / 2][OUT_CH + 1];
  __shared__ float sh[32][HID];
  for (int i = threadIdx.x; i < OUT_CH * (HID / 2); i += 256) {
    int o = i >> 5, c2 = i & 31;
    float a = W2l[o * HID + 2 * c2], b = W2l[o * HID + 2 * c2 + 1];
    sWl[c2][o] = (unsigned)f2bf(a) | ((unsigned)f2bf(b) << 16);
    float c = W2r[o * HID + 2 * c2], d = W2r[o * HID + 2 * c2 + 1];
    sWr[c2][o] = (unsigned)f2bf(c) | ((unsigned)f2bf(d) << 16);
  }
  int nblk = blockIdx.x * 32;
  for (int s = threadIdx.x; s < 32 * (HID / 4); s += 256) {
    int node = s >> 4, c4 = s & 15;
    int n = nblk + node;
    float4 v = make_float4(0.f, 0.f, 0.f, 0.f);
    if (n < N_NODES)
      v = *reinterpret_cast<const float4*>(h1 + (size_t)n * HID + c4 * 4);
    *reinterpret_cast<float4*>(&sh[node][c4 * 4]) = v;
  }
  __syncthreads();

  int wave = threadIdx.x >> 6, lane = threadIdx.x & 63;
  int n0 = nblk + wave * 8;
  if (n0 >= N_NODES || lane >= OUT_CH) return;
  float bias = b2[lane];

  float accl[8], accr[8];
#pragma unroll
  for (int i = 0; i < 8; ++i) {
    accl[i] = 0.f;
    accr[i] = bias;
  }
  const int nb = wave * 8;
  int nvalid = min(8, N_NODES - n0);
  for (int c = 0; c < HID; c += 4) {
    unsigned ul0 = sWl[(c >> 1) + 0][lane], ul1 = sWl[(c >> 1) + 1][lane];
    unsigned ur0 = sWr[(c >> 1) + 0][lane], ur1 = sWr[(c >> 1) + 1][lane];
    float wl0 = bflo(ul0), wl1 = bfhi(ul0), wl2 = bflo(ul1), wl3 = bfhi(ul1);
    float wr0 = bflo(ur0), wr1 = bfhi(ur0), wr2 = bflo(ur1), wr3 = bfhi(ur1);
#pragma unroll
    for (int i = 0; i < 8; ++i) {
      const float4 hv = *reinterpret_cast<const float4*>(&sh[nb + i][c]);
      accl[i] = fmaf(hv.x, wl0, accl[i]);
      accr[i] = fmaf(hv.x, wr0, accr[i]);
      accl[i] = fmaf(hv.y, wl1, accl[i]);
      accr[i] = fmaf(hv.y, wr1, accr[i]);
      accl[i] = fmaf(hv.z, wl2, accl[i]);
      accr[i] = fmaf(hv.z, wr2, accr[i]);
      accl[i] = fmaf(hv.w, wl3, accl[i]);
      accr[i] = fmaf(hv.w, wr3, accr[i]);
    }
  }
  for (int i = 0; i < nvalid; ++i) {
    hw2[(size_t)(n0 + i) * OUT_CH + lane] = f2bf(accl[i]);
    self2[(size_t)(n0 + i) * OUT_CH + lane] = accr[i];
  }
}

// out = log_softmax(gather_mean(hw2) + self2) — no LDS, 16-wide exact-deg
__global__ __launch_bounds__(256) void agg2_kernel(
    const ushort* __restrict__ hw2, const float* __restrict__ self2,
    const int* __restrict__ cnt, const int* __restrict__ off,
    const int* __restrict__ csr, float* __restrict__ out) {
  int wave = threadIdx.x >> 6, lane = threadIdx.x & 63;
  int n = blockIdx.x * 4 + wave;
  if (n >= N_NODES) return;

  int deg = cnt[n], base = off[n];
  float logit = -1e30f;
  if (lane < OUT_CH) {
    float acc = 0.f;
    int k = 0;
    for (; k + 16 <= deg; k += 16) {
      int e[16];
#pragma unroll
      for (int j = 0; j < 16; ++j) e[j] = csr[base + k + j];
      float v[16];
#pragma unroll
      for (int j = 0; j < 16; ++j)
        v[j] = bf2f(hw2[(size_t)e[j] * OUT_CH + lane]);
#pragma unroll
      for (int j = 0; j < 16; ++j) acc += v[j];
    }
    if (k + 8 <= deg) {
      int e[8];
#pragma unroll
      for (int j = 0; j < 8; ++j) e[j] = csr[base + k + j];
      float v[8];
#pragma unroll
      for (int j = 0; j < 8; ++j)
        v[j] = bf2f(hw2[(size_t)e[j] * OUT_CH + lane]);
#pragma unroll
      for (int j = 0; j < 8; ++j) acc += v[j];
      k += 8;
    }
    if (k < deg) {
#pragma unroll
      for (int i = 0; i < 8; ++i) {
        int kk = k + i;
        int s_ = csr[base + (kk < deg ? kk : k)];
        float v = bf2f(hw2[(size_t)s_ * OUT_CH + lane]);
        if (kk < deg) acc += v;
      }
    }
    logit = acc / fmaxf((float)deg, 1.0f) + self2[(size_t)n * OUT_CH + lane];
  }
  float m = logit;
  for (int o = 32; o; o >>= 1) m = fmaxf(m, __shfl_xor(m, o));
  float e = (lane < OUT_CH) ? expf(logit - m) : 0.f;
  float ssum = e;
  for (int o = 32; o; o >>= 1) ssum += __shfl_xor(ssum, o);
  float lse = logf(ssum);
  if (lane < OUT_CH) out[(size_t)n * OUT_CH + lane] = logit - m - lse;
}

extern "C" void kernel_launch(void* const* d_in, const int* in_sizes, int n_in,
                              void* d_out, int out_size, void* d_ws, size_t ws_size,
                              hipStream_t stream) {
  const float* x   = (const float*)d_in[0];
  const int*   ei  = (const int*)d_in[1];
  const float* W1l = (const float*)d_in[2];
  const float* b1  = (const float*)d_in[3];
  const float* W1r = (const float*)d_in[4];
  const float* W2l = (const float*)d_in[5];
  const float* b2  = (const float*)d_in[6];
  const float* W2r = (const float*)d_in[7];
  float* out = (float*)d_out;

  const int* src = ei;            // edge_index[0]
  const int* dst = ei + N_EDGES;  // edge_index[1]

  // ws layout — pairbuf does not alias xwr (xform1 runs inside histX)
  float* xwr   = (float*)d_ws;                             // [N*HID] f32
  float* self2 = xwr + (size_t)N_NODES * HID;              // [N*OUT_CH] f32
  float* h1    = self2 + (size_t)N_NODES * OUT_CH;         // [N*HID] f32
  ushort* xwl  = (ushort*)(h1 + (size_t)N_NODES * HID);    // [N*HID] bf16
  ushort* hw2  = xwl + (size_t)N_NODES * HID;              // [N*OUT_CH] bf16
  unsigned* pairbuf = (unsigned*)(hw2 + (size_t)N_NODES * OUT_CH);  // [E]
  int* blkcnt = (int*)(pairbuf + N_EDGES);                 // [NSEG]
  int* segoff = blkcnt + NSEG;                             // [NSEG]
  int* asum   = segoff + NSEG;                             // [256]
  int* cnt    = asum + 256;                                // [N]
  int* off    = cnt + N_NODES;                             // [N]
  int* csr    = off + N_NODES;                             // [E]

  // merged histogram + xform1 (independent work, overlapped)
  histX_kernel<<<NBLK + NXBLK, 256, 0, stream>>>(dst, blkcnt, x, W1l, W1r, b1,
                                                 xwl, xwr);
  scanA_kernel<<<NSCANA, 256, 0, stream>>>(blkcnt, segoff, asum);
  scanB_kernel<<<1, 256, 0, stream>>>(asum);
  placeB_kernel<<<NBLK, 256, 0, stream>>>(src, dst, segoff, asum, pairbuf);
  placeC_kernel<<<NBUCKETS, 256, 0, stream>>>(pairbuf, segoff, asum, cnt, off,
                                              csr);

  agg1_kernel<<<(N_NODES + 3) / 4, 256, 0, stream>>>(xwl, xwr, cnt, off, csr,
                                                     h1);
  xform2_kernel<<<(N_NODES + 31) / 32, 256, 0, stream>>>(h1, W2l, W2r, b2, hw2,
                                                         self2);
  agg2_kernel<<<(N_NODES + 3) / 4, 256, 0, stream>>>(hw2, self2, cnt, off, csr,
                                                     out);
}

// Round 20
// 116.627 us; speedup vs baseline: 1.1426x; 1.0228x over previous
//
#include <hip/hip_runtime.h>

#define N_NODES 50000
#define N_EDGES 800000
#define IN_CH 128
#define HID 64
#define OUT_CH 40
#define BSHIFT 7
#define BNODES 128    // nodes per bucket
#define NBUCKETS 391  // ceil(50000/128)
#define NBLK 256      // edge-pass blocks
#define EPB 3125      // edges per block (256*3125 = 800000 exactly)
#define NSEG (NBUCKETS * NBLK)  // 100096 (bucket-major: i = (b<<8)|blk)
#define SCHUNK 1024
#define NSCANA ((NSEG + SCHUNK - 1) / SCHUNK)  // 98
#define MAXB 4096     // placeC LDS slot capacity (expected 2048, +45 sigma)
#define NXBLK 782     // ceil(50000/64) xform1 blocks

// ---------------------------------------------------------------------------
// CSR gather, no fp atomics, transform-before-aggregate.
//   histX:  [blocks 0..255] per-block LDS bucket histogram  (overlapped with)
//           [blocks 256+ ]  MFMA xform1: xwl=bf16(x@W1l.T), xwr=x@W1r.T+b1
//   scanA:  level-1 scan of blkcnt -> segoff + raw block sums asum
//           (scanB folded into placeB/placeC: each block LDS-scans asum[98])
//   placeB: LDS cursors; packed (src<<7|dstlocal) pairs -> contiguous segments
//   placeC: per bucket: LDS degree count + scan -> cnt/off; LDS-place -> csr
//   agg1:   h1 = relu(gather_mean(xwl) + xwr)   [1 node/wave, 4 edge slots x
//           uint2 (4ch) loads — VMEM issues halved vs paired-uint]
//   xform2: hw2 = bf16(h1@W2l.T), self2 = h1@W2r.T + b2
//   agg2:   out = log_softmax(gather_mean(hw2) + self2)  [16-wide exact-deg]
// ---------------------------------------------------------------------------

typedef __attribute__((ext_vector_type(8))) short short8v;
typedef __attribute__((ext_vector_type(4))) float float4v;

__device__ __forceinline__ unsigned f2bf_u(float f) {
  unsigned u = __float_as_uint(f);
  return (u + 0x7FFF + ((u >> 16) & 1)) >> 16;  // RNE
}
__device__ __forceinline__ ushort f2bf(float f) { return (ushort)f2bf_u(f); }
__device__ __forceinline__ float bf2f(ushort u) {
  return __uint_as_float(((unsigned)u) << 16);
}
__device__ __forceinline__ float bflo(unsigned u) {
  return __uint_as_float(u << 16);
}
__device__ __forceinline__ float bfhi(unsigned u) {
  return __uint_as_float(u & 0xFFFF0000u);
}

// pack 8 consecutive floats -> 8 bf16 in a uint4
__device__ __forceinline__ uint4 pack8(const float* p) {
  float4 a = *reinterpret_cast<const float4*>(p);
  float4 b = *reinterpret_cast<const float4*>(p + 4);
  uint4 r;
  r.x = f2bf_u(a.x) | (f2bf_u(a.y) << 16);
  r.y = f2bf_u(a.z) | (f2bf_u(a.w) << 16);
  r.z = f2bf_u(b.x) | (f2bf_u(b.y) << 16);
  r.w = f2bf_u(b.z) | (f2bf_u(b.w) << 16);
  return r;
}

// merged: blocks [0,NBLK) histogram; blocks [NBLK, NBLK+NXBLK) MFMA xform1
__global__ __launch_bounds__(256) void histX_kernel(
    const int* __restrict__ dst, int* __restrict__ blkcnt,
    const float* __restrict__ x, const float* __restrict__ W1l,
    const float* __restrict__ W1r, const float* __restrict__ b1,
    ushort* __restrict__ xwl, float* __restrict__ xwr) {
  __shared__ int h[NBUCKETS];
  __shared__ ushort sWl[64 * 128];  // 16 KB, swizzle byte^=(row&15)<<4
  __shared__ ushort sWr[64 * 128];
  __shared__ ushort sx[64 * 128];
  __shared__ float sb[64];

  if (blockIdx.x < NBLK) {
    // ---- histogram path ----
    for (int i = threadIdx.x; i < NBUCKETS; i += 256) h[i] = 0;
    __syncthreads();
    int blk = blockIdx.x;
    int e0 = blk * EPB, e1 = min(e0 + EPB, N_EDGES);
    for (int e = e0 + threadIdx.x; e < e1; e += 256)
      atomicAdd(&h[dst[e] >> BSHIFT], 1);
    __syncthreads();
    for (int i = threadIdx.x; i < NBUCKETS; i += 256)
      blkcnt[(i << 8) | blk] = h[i];
    return;
  }

  // ---- MFMA xform1 path ----
  int nblk = (blockIdx.x - NBLK) * 64;
  for (int q = threadIdx.x; q < 1024; q += 256) {
    int row = q >> 4, c8 = (q & 15) << 3;
    int boff = row * 256 + (((c8 << 1)) ^ ((row & 15) << 4));
    int n = nblk + row;
    uint4 p = make_uint4(0, 0, 0, 0);
    if (n < N_NODES) p = pack8(x + (size_t)n * IN_CH + c8);
    *reinterpret_cast<uint4*>((char*)sx + boff) = p;
  }
  for (int q = threadIdx.x; q < 1024; q += 256) {
    int row = q >> 4, c8 = (q & 15) << 3;
    int boff = row * 256 + (((c8 << 1)) ^ ((row & 15) << 4));
    *reinterpret_cast<uint4*>((char*)sWl + boff) =
        pack8(W1l + row * IN_CH + c8);
    *reinterpret_cast<uint4*>((char*)sWr + boff) =
        pack8(W1r + row * IN_CH + c8);
  }
  if (threadIdx.x < 64) sb[threadIdx.x] = b1[threadIdx.x];
  __syncthreads();

  int wave = threadIdx.x >> 6, lane = threadIdx.x & 63;
  int nloc = lane & 15, g = lane >> 4;

  float4v accl[4], accr[4];
#pragma unroll
  for (int m = 0; m < 4; ++m) {
    accl[m] = (float4v){0.f, 0.f, 0.f, 0.f};
    accr[m] = (float4v){0.f, 0.f, 0.f, 0.f};
  }

  int xrow = wave * 16 + nloc;
#pragma unroll
  for (int kt = 0; kt < 4; ++kt) {
    int cb = kt * 64 + g * 16;
    short8v bx = *reinterpret_cast<const short8v*>(
        (char*)sx + xrow * 256 + (cb ^ ((xrow & 15) << 4)));
#pragma unroll
    for (int m = 0; m < 4; ++m) {
      int wrow = m * 16 + nloc;
      int so = wrow * 256 + (cb ^ ((wrow & 15) << 4));
      short8v al = *reinterpret_cast<const short8v*>((char*)sWl + so);
      short8v ar = *reinterpret_cast<const short8v*>((char*)sWr + so);
      accl[m] = __builtin_amdgcn_mfma_f32_16x16x32_bf16(al, bx, accl[m], 0, 0, 0);
      accr[m] = __builtin_amdgcn_mfma_f32_16x16x32_bf16(ar, bx, accr[m], 0, 0, 0);
    }
  }

  int n = nblk + wave * 16 + nloc;
  if (n < N_NODES) {
#pragma unroll
    for (int m = 0; m < 4; ++m) {
      int h0 = m * 16 + g * 4;
      uint2 pl;
      pl.x = f2bf_u(accl[m][0]) | (f2bf_u(accl[m][1]) << 16);
      pl.y = f2bf_u(accl[m][2]) | (f2bf_u(accl[m][3]) << 16);
      *reinterpret_cast<uint2*>(xwl + (size_t)n * HID + h0) = pl;
      float4 vr;
      vr.x = accr[m][0] + sb[h0 + 0];
      vr.y = accr[m][1] + sb[h0 + 1];
      vr.z = accr[m][2] + sb[h0 + 2];
      vr.w = accr[m][3] + sb[h0 + 3];
      *reinterpret_cast<float4*>(xwr + (size_t)n * HID + h0) = vr;
    }
  }
}

// level-1 scan: 1024 elems/block (4/thread, coalesced); asum = raw block sums
__global__ __launch_bounds__(256) void scanA_kernel(
    const int* __restrict__ blkcnt, int* __restrict__ segoff,
    int* __restrict__ asum) {
  __shared__ int s[256];
  int t = threadIdx.x;
  int idx0 = blockIdx.x * SCHUNK + t * 4;
  int v[4], tot = 0;
#pragma unroll
  for (int j = 0; j < 4; ++j) {
    int i = idx0 + j;
    v[j] = (i < NSEG) ? blkcnt[i] : 0;
    tot += v[j];
  }
  s[t] = tot;
  __syncthreads();
  for (int o = 1; o < 256; o <<= 1) {
    int u = (t >= o) ? s[t - o] : 0;
    __syncthreads();
    s[t] += u;
    __syncthreads();
  }
  int pre = s[t] - tot;
#pragma unroll
  for (int j = 0; j < 4; ++j) {
    int i = idx0 + j;
    if (i < NSEG) segoff[i] = pre;
    pre += v[j];
  }
  if (t == 255) asum[blockIdx.x] = s[255];
}

// bin packed pairs into per-(block,bucket) contiguous segments (LDS cursors);
// asum exclusive-prefix computed in-block (scanB folded here)
__global__ __launch_bounds__(256) void placeB_kernel(
    const int* __restrict__ src, const int* __restrict__ dst,
    const int* __restrict__ segoff, const int* __restrict__ asum,
    unsigned* __restrict__ pairbuf) {
  __shared__ int cur[NBUCKETS];
  __shared__ int spre[256];
  int t = threadIdx.x;
  int av = (t < NSCANA) ? asum[t] : 0;
  spre[t] = av;
  __syncthreads();
  for (int o = 1; o < 256; o <<= 1) {
    int u = (t >= o) ? spre[t - o] : 0;
    __syncthreads();
    spre[t] += u;
    __syncthreads();
  }
  int excl = spre[t] - av;
  __syncthreads();
  spre[t] = excl;
  __syncthreads();
  int blk = blockIdx.x;
  for (int b = t; b < NBUCKETS; b += 256) {
    int i = (b << 8) | blk;
    cur[b] = segoff[i] + spre[i >> 10];
  }
  __syncthreads();
  int e0 = blk * EPB, e1 = min(e0 + EPB, N_EDGES);
  for (int e = e0 + t; e < e1; e += 256) {
    int d = dst[e];
    int pos = atomicAdd(&cur[d >> BSHIFT], 1);  // LDS atomic
    pairbuf[pos] = ((unsigned)src[e] << BSHIFT) | (unsigned)(d & (BNODES - 1));
  }
}

// per bucket: degree-count + LDS scan -> cnt/off (coalesced); place -> csr
__global__ __launch_bounds__(256) void placeC_kernel(
    const unsigned* __restrict__ pairbuf, const int* __restrict__ segoff,
    const int* __restrict__ asum, int* __restrict__ cnt,
    int* __restrict__ off, int* __restrict__ csr) {
  __shared__ int lcnt[BNODES];
  __shared__ int woff[BNODES];
  __shared__ int lcur[BNODES];
  __shared__ int sscan[256];
  __shared__ int slot[MAXB];
  int t = threadIdx.x;
  // in-block exclusive prefix of asum (scanB folded here)
  int av = (t < NSCANA) ? asum[t] : 0;
  sscan[t] = av;
  __syncthreads();
  for (int o = 1; o < 256; o <<= 1) {
    int u = (t >= o) ? sscan[t - o] : 0;
    __syncthreads();
    sscan[t] += u;
    __syncthreads();
  }
  int excl = sscan[t] - av;
  __syncthreads();
  sscan[t] = excl;
  __syncthreads();

  int b = blockIdx.x;
  int i0 = b << 8;
  int start = segoff[i0] + sscan[i0 >> 10];
  int end = N_EDGES;
  if (b != NBUCKETS - 1) {
    int i1 = (b + 1) << 8;
    end = segoff[i1] + sscan[i1 >> 10];
  }
  __syncthreads();  // sscan reused below for node scan

  int n0 = b << BSHIFT;
  int nn = min(BNODES, N_NODES - n0);
  int len = end - start;
  for (int i = t; i < nn; i += 256) {
    lcnt[i] = 0;
    lcur[i] = 0;
  }
  __syncthreads();
  for (int p = start + t; p < end; p += 256)
    atomicAdd(&lcnt[pairbuf[p] & (BNODES - 1)], 1);
  __syncthreads();
  int v = (t < nn) ? lcnt[t] : 0;
  sscan[t] = v;
  __syncthreads();
  for (int o = 1; o < 256; o <<= 1) {
    int t2 = (t >= o) ? sscan[t - o] : 0;
    __syncthreads();
    sscan[t] += t2;
    __syncthreads();
  }
  if (t < nn) {
    woff[t] = sscan[t] - v;
    cnt[n0 + t] = v;
    off[n0 + t] = start + sscan[t] - v;
  }
  __syncthreads();
  if (len <= MAXB) {
    for (int p = start + t; p < end; p += 256) {
      unsigned e = pairbuf[p];
      int local = (int)(e & (BNODES - 1));
      int pos = woff[local] + atomicAdd(&lcur[local], 1);
      slot[pos] = (int)(e >> BSHIFT);
    }
    __syncthreads();
    for (int p = t; p < len; p += 256) csr[start + p] = slot[p];
  } else {  // statistical-overflow fallback
    for (int p = start + t; p < end; p += 256) {
      unsigned e = pairbuf[p];
      int local = (int)(e & (BNODES - 1));
      int pos = woff[local] + atomicAdd(&lcur[local], 1);
      csr[start + pos] = (int)(e >> BSHIFT);
    }
  }
}

// h1 = relu(gather_mean(xwl) + xwr) — 1 node/wave, 4 edge slots x uint2 loads
__global__ __launch_bounds__(256) void agg1_kernel(
    const ushort* __restrict__ xwl, const float* __restrict__ xwr,
    const int* __restrict__ cnt, const int* __restrict__ off,
    const int* __restrict__ csr, float* __restrict__ h1) {
  int wave = threadIdx.x >> 6, lane = threadIdx.x & 63;
  int n = blockIdx.x * 4 + wave;
  if (n >= N_NODES) return;

  int deg = cnt[n], base = off[n];
  int es = lane >> 4;  // edge slot 0..3
  int cq = lane & 15;  // channel quad (4 ch: 4*cq..4*cq+3)
  float a0 = 0.f, a1 = 0.f, a2 = 0.f, a3 = 0.f;

  if (deg > 0) {
    int k = 0;
    for (; k + 16 <= deg; k += 16) {  // 16 edges in flight (4 slots x 4)
      int e[4];
#pragma unroll
      for (int j = 0; j < 4; ++j) e[j] = csr[base + k + 4 * j + es];
      uint2 u[4];
#pragma unroll
      for (int j = 0; j < 4; ++j)
        u[j] = *reinterpret_cast<const uint2*>(xwl + (size_t)e[j] * HID +
                                               4 * cq);
#pragma unroll
      for (int j = 0; j < 4; ++j) {
        a0 += bflo(u[j].x);
        a1 += bfhi(u[j].x);
        a2 += bflo(u[j].y);
        a3 += bfhi(u[j].y);
      }
    }
    if (k + 8 <= deg) {  // 8-edge mid chunk
      int e[2];
#pragma unroll
      for (int j = 0; j < 2; ++j) e[j] = csr[base + k + 4 * j + es];
      uint2 u[2];
#pragma unroll
      for (int j = 0; j < 2; ++j)
        u[j] = *reinterpret_cast<const uint2*>(xwl + (size_t)e[j] * HID +
                                               4 * cq);
#pragma unroll
      for (int j = 0; j < 2; ++j) {
        a0 += bflo(u[j].x);
        a1 += bfhi(u[j].x);
        a2 += bflo(u[j].y);
        a3 += bfhi(u[j].y);
      }
      k += 8;
    }
    if (k < deg) {  // masked remainder (<8 edges, 2 j-iterations)
#pragma unroll
      for (int j = 0; j < 2; ++j) {
        int idx = k + 4 * j + es;
        bool valid = idx < deg;
        int e = csr[base + (valid ? idx : 0)];
        uint2 u =
            *reinterpret_cast<const uint2*>(xwl + (size_t)e * HID + 4 * cq);
        if (valid) {
          a0 += bflo(u.x);
          a1 += bfhi(u.x);
          a2 += bflo(u.y);
          a3 += bfhi(u.y);
        }
      }
    }
    a0 += __shfl_xor(a0, 16);
    a0 += __shfl_xor(a0, 32);
    a1 += __shfl_xor(a1, 16);
    a1 += __shfl_xor(a1, 32);
    a2 += __shfl_xor(a2, 16);
    a2 += __shfl_xor(a2, 32);
    a3 += __shfl_xor(a3, 16);
    a3 += __shfl_xor(a3, 32);
  }

  if (es == 0) {
    float inv = 1.0f / fmaxf((float)deg, 1.0f);
    const float4 s =
        *reinterpret_cast<const float4*>(xwr + (size_t)n * HID + 4 * cq);
    float4 h;
    h.x = fmaxf(a0 * inv + s.x, 0.f);
    h.y = fmaxf(a1 * inv + s.y, 0.f);
    h.z = fmaxf(a2 * inv + s.z, 0.f);
    h.w = fmaxf(a3 * inv + s.w, 0.f);
    *reinterpret_cast<float4*>(h1 + (size_t)n * HID + 4 * cq) = h;
  }
}

// hw2[n,o] = bf16(h1[n,:].W2l[o,:]);  self2[n,o] = h1[n,:].W2r[o,:] + b2[o]
__global__ __launch_bounds__(256) void xform2_kernel(
    const float* __restrict__ h1, const float* __restrict__ W2l,
    const float* __restrict__ W2r, const float* __restrict__ b2,
    ushort* __restrict__ hw2, float* __restrict__ self2) {
  __shared__ unsigned sWl[HID / 2][OUT_CH + 1];
  __shared__ unsigned sWr[HID / 2][OUT_CH + 1];
  __shared__ float sh[32][HID];
  for (int i = threadIdx.x; i < OUT_CH * (HID / 2); i += 256) {
    int o = i >> 5, c2 = i & 31;
    float a = W2l[o * HID + 2 * c2], b = W2l[o * HID + 2 * c2 + 1];
    sWl[c2][o] = (unsigned)f2bf(a) | ((unsigned)f2bf(b) << 16);
    float c = W2r[o * HID + 2 * c2], d = W2r[o * HID + 2 * c2 + 1];
    sWr[c2][o] = (unsigned)f2bf(c) | ((unsigned)f2bf(d) << 16);
  }
  int nblk = blockIdx.x * 32;
  for (int s = threadIdx.x; s < 32 * (HID / 4); s += 256) {
    int node = s >> 4, c4 = s & 15;
    int n = nblk + node;
    float4 v = make_float4(0.f, 0.f, 0.f, 0.f);
    if (n < N_NODES)
      v = *reinterpret_cast<const float4*>(h1 + (size_t)n * HID + c4 * 4);
    *reinterpret_cast<float4*>(&sh[node][c4 * 4]) = v;
  }
  __syncthreads();

  int wave = threadIdx.x >> 6, lane = threadIdx.x & 63;
  int n0 = nblk + wave * 8;
  if (n0 >= N_NODES || lane >= OUT_CH) return;
  float bias = b2[lane];

  float accl[8], accr[8];
#pragma unroll
  for (int i = 0; i < 8; ++i) {
    accl[i] = 0.f;
    accr[i] = bias;
  }
  const int nb = wave * 8;
  int nvalid = min(8, N_NODES - n0);
  for (int c = 0; c < HID; c += 4) {
    unsigned ul0 = sWl[(c >> 1) + 0][lane], ul1 = sWl[(c >> 1) + 1][lane];
    unsigned ur0 = sWr[(c >> 1) + 0][lane], ur1 = sWr[(c >> 1) + 1][lane];
    float wl0 = bflo(ul0), wl1 = bfhi(ul0), wl2 = bflo(ul1), wl3 = bfhi(ul1);
    float wr0 = bflo(ur0), wr1 = bfhi(ur0), wr2 = bflo(ur1), wr3 = bfhi(ur1);
#pragma unroll
    for (int i = 0; i < 8; ++i) {
      const float4 hv = *reinterpret_cast<const float4*>(&sh[nb + i][c]);
      accl[i] = fmaf(hv.x, wl0, accl[i]);
      accr[i] = fmaf(hv.x, wr0, accr[i]);
      accl[i] = fmaf(hv.y, wl1, accl[i]);
      accr[i] = fmaf(hv.y, wr1, accr[i]);
      accl[i] = fmaf(hv.z, wl2, accl[i]);
      accr[i] = fmaf(hv.z, wr2, accr[i]);
      accl[i] = fmaf(hv.w, wl3, accl[i]);
      accr[i] = fmaf(hv.w, wr3, accr[i]);
    }
  }
  for (int i = 0; i < nvalid; ++i) {
    hw2[(size_t)(n0 + i) * OUT_CH + lane] = f2bf(accl[i]);
    self2[(size_t)(n0 + i) * OUT_CH + lane] = accr[i];
  }
}

// out = log_softmax(gather_mean(hw2) + self2) — no LDS, 16-wide exact-deg
__global__ __launch_bounds__(256) void agg2_kernel(
    const ushort* __restrict__ hw2, const float* __restrict__ self2,
    const int* __restrict__ cnt, const int* __restrict__ off,
    const int* __restrict__ csr, float* __restrict__ out) {
  int wave = threadIdx.x >> 6, lane = threadIdx.x & 63;
  int n = blockIdx.x * 4 + wave;
  if (n >= N_NODES) return;

  int deg = cnt[n], base = off[n];
  float logit = -1e30f;
  if (lane < OUT_CH) {
    float acc = 0.f;
    int k = 0;
    for (; k + 16 <= deg; k += 16) {
      int e[16];
#pragma unroll
      for (int j = 0; j < 16; ++j) e[j] = csr[base + k + j];
      float v[16];
#pragma unroll
      for (int j = 0; j < 16; ++j)
        v[j] = bf2f(hw2[(size_t)e[j] * OUT_CH + lane]);
#pragma unroll
      for (int j = 0; j < 16; ++j) acc += v[j];
    }
    if (k + 8 <= deg) {
      int e[8];
#pragma unroll
      for (int j = 0; j < 8; ++j) e[j] = csr[base + k + j];
      float v[8];
#pragma unroll
      for (int j = 0; j < 8; ++j)
        v[j] = bf2f(hw2[(size_t)e[j] * OUT_CH + lane]);
#pragma unroll
      for (int j = 0; j < 8; ++j) acc += v[j];
      k += 8;
    }
    if (k < deg) {
#pragma unroll
      for (int i = 0; i < 8; ++i) {
        int kk = k + i;
        int s_ = csr[base + (kk < deg ? kk : k)];
        float v = bf2f(hw2[(size_t)s_ * OUT_CH + lane]);
        if (kk < deg) acc += v;
      }
    }
    logit = acc / fmaxf((float)deg, 1.0f) + self2[(size_t)n * OUT_CH + lane];
  }
  float m = logit;
  for (int o = 32; o; o >>= 1) m = fmaxf(m, __shfl_xor(m, o));
  float e = (lane < OUT_CH) ? expf(logit - m) : 0.f;
  float ssum = e;
  for (int o = 32; o; o >>= 1) ssum += __shfl_xor(ssum, o);
  float lse = logf(ssum);
  if (lane < OUT_CH) out[(size_t)n * OUT_CH + lane] = logit - m - lse;
}

extern "C" void kernel_launch(void* const* d_in, const int* in_sizes, int n_in,
                              void* d_out, int out_size, void* d_ws, size_t ws_size,
                              hipStream_t stream) {
  const float* x   = (const float*)d_in[0];
  const int*   ei  = (const int*)d_in[1];
  const float* W1l = (const float*)d_in[2];
  const float* b1  = (const float*)d_in[3];
  const float* W1r = (const float*)d_in[4];
  const float* W2l = (const float*)d_in[5];
  const float* b2  = (const float*)d_in[6];
  const float* W2r = (const float*)d_in[7];
  float* out = (float*)d_out;

  const int* src = ei;            // edge_index[0]
  const int* dst = ei + N_EDGES;  // edge_index[1]

  // ws layout — pairbuf does not alias xwr (xform1 runs inside histX)
  float* xwr   = (float*)d_ws;                             // [N*HID] f32
  float* self2 = xwr + (size_t)N_NODES * HID;              // [N*OUT_CH] f32
  float* h1    = self2 + (size_t)N_NODES * OUT_CH;         // [N*HID] f32
  ushort* xwl  = (ushort*)(h1 + (size_t)N_NODES * HID);    // [N*HID] bf16
  ushort* hw2  = xwl + (size_t)N_NODES * HID;              // [N*OUT_CH] bf16
  unsigned* pairbuf = (unsigned*)(hw2 + (size_t)N_NODES * OUT_CH);  // [E]
  int* blkcnt = (int*)(pairbuf + N_EDGES);                 // [NSEG]
  int* segoff = blkcnt + NSEG;                             // [NSEG]
  int* asum   = segoff + NSEG;                             // [256]
  int* cnt    = asum + 256;                                // [N]
  int* off    = cnt + N_NODES;                             // [N]
  int* csr    = off + N_NODES;                             // [E]

  // merged histogram + xform1 (independent work, overlapped)
  histX_kernel<<<NBLK + NXBLK, 256, 0, stream>>>(dst, blkcnt, x, W1l, W1r, b1,
                                                 xwl, xwr);
  scanA_kernel<<<NSCANA, 256, 0, stream>>>(blkcnt, segoff, asum);
  placeB_kernel<<<NBLK, 256, 0, stream>>>(src, dst, segoff, asum, pairbuf);
  placeC_kernel<<<NBUCKETS, 256, 0, stream>>>(pairbuf, segoff, asum, cnt, off,
                                              csr);

  agg1_kernel<<<(N_NODES + 3) / 4, 256, 0, stream>>>(xwl, xwr, cnt, off, csr,
                                                     h1);
  xform2_kernel<<<(N_NODES + 31) / 32, 256, 0, stream>>>(h1, W2l, W2r, b2, hw2,
                                                         self2);
  agg2_kernel<<<(N_NODES + 3) / 4, 256, 0, stream>>>(hw2, self2, cnt, off, csr,
                                                     out);
}